// Round 4
// baseline (1888.217 us; speedup 1.0000x reference)
//
#include <hip/hip_runtime.h>

#define N_NODES 100000
#define N_EDGES 20000
#define NNZV    1600000
#define NSEG    (N_EDGES + N_NODES)
#define FIN     128
#define NPART   8
#define E_PER_P (N_EDGES / NPART)   // 2500
#define N_PER_P (N_NODES / NPART)   // 12500
#define HSLICES 32

// Feature layouts:
//  x_blk / h_blk : blocked-8,  [16 groups][100000 rows][8 cols]   (group g = cols 8g..8g+7)
//  ebuf_blk      : blocked-8,  [16 groups][20000 rows][8 cols]
//  ebuf2_blk     : blocked-16, [FOUT/16 groups][20000 rows][16 cols]

// ---------------- histogram count (LDS, atomic-free at device scope) ----------------

__global__ __launch_bounds__(256) void k_hist(const int* __restrict__ nidx,
                                              const int* __restrict__ eidx,
                                              int* __restrict__ part) {
  __shared__ int hist[12544];
  int r = blockIdx.x % 10, s = blockIdx.x / 10;
  const int* arr; int base, size, bin_off;
  if (r < 2) { arr = eidx; base = r * 10000; size = 10000; bin_off = r * 10000; }
  else { int ri = r - 2; arr = nidx; base = ri * N_PER_P; size = N_PER_P; bin_off = N_EDGES + ri * N_PER_P; }
  for (int i = threadIdx.x; i < size; i += 256) hist[i] = 0;
  __syncthreads();
  int lo = s * (NNZV / HSLICES), hi = lo + (NNZV / HSLICES);  // 50000 per slice
  for (int i = lo + threadIdx.x; i < hi; i += 256) {
    int v = __builtin_nontemporal_load(arr + i);
    unsigned d = (unsigned)(v - base);
    if (d < (unsigned)size) atomicAdd(&hist[d], 1);
  }
  __syncthreads();
  int* dst = part + (size_t)s * NSEG + bin_off;
  for (int i = threadIdx.x; i < size; i += 256) dst[i] = hist[i];
}

__global__ void k_hreduce(const int* __restrict__ part, int* __restrict__ cnt) {
  int b = blockIdx.x * 256 + threadIdx.x;
  if (b >= NSEG) return;
  int sum = 0;
#pragma unroll
  for (int s = 0; s < HSLICES; ++s) sum += part[(size_t)s * NSEG + b];
  cnt[b] = sum;
}

// ---------------- scans ----------------

__global__ void k_scan1(const int* __restrict__ cnt, int* __restrict__ incl,
                        int* __restrict__ bsum) {
  __shared__ int s[1024];
  int gid = blockIdx.x * 1024 + threadIdx.x;
  int v = (gid < NSEG) ? cnt[gid] : 0;
  s[threadIdx.x] = v;
  __syncthreads();
  for (int d = 1; d < 1024; d <<= 1) {
    int t = (threadIdx.x >= d) ? s[threadIdx.x - d] : 0;
    __syncthreads();
    s[threadIdx.x] += t;
    __syncthreads();
  }
  if (gid < NSEG) incl[gid] = s[threadIdx.x];
  if (threadIdx.x == 1023) bsum[blockIdx.x] = s[1023];
}

__global__ void k_scan2(int* __restrict__ bsum, int nb) {
  __shared__ int s[128];
  int v = (threadIdx.x < nb) ? bsum[threadIdx.x] : 0;
  s[threadIdx.x] = v;
  __syncthreads();
  for (int d = 1; d < 128; d <<= 1) {
    int t = (threadIdx.x >= (unsigned)d) ? s[threadIdx.x - d] : 0;
    __syncthreads();
    s[threadIdx.x] += t;
    __syncthreads();
  }
  if (threadIdx.x < nb) bsum[threadIdx.x] = s[threadIdx.x] - v;  // exclusive
}

__global__ void k_scan3(int* __restrict__ off, const int* __restrict__ cnt,
                        const int* __restrict__ bsum) {
  int gid = blockIdx.x * 1024 + threadIdx.x;
  if (gid < NSEG) off[gid] = off[gid] - cnt[gid] + bsum[blockIdx.x];
}

// ---------------- fill (destination-partitioned) ----------------

__global__ void k_fill(const int* __restrict__ nidx, const int* __restrict__ eidx,
                       const int* __restrict__ off, int* __restrict__ cur,
                       int* __restrict__ csr) {
  int p = blockIdx.x & (NPART - 1);
  int e_lo = p * E_PER_P, e_hi = e_lo + E_PER_P;
  int n_lo = p * N_PER_P, n_hi = n_lo + N_PER_P;
  int i = (blockIdx.x >> 3) * blockDim.x + threadIdx.x;
  int st = (gridDim.x >> 3) * blockDim.x;
  for (; i < NNZV; i += st) {
    int e = eidx[i], n = nidx[i];
    if (e >= e_lo && e < e_hi) {
      int pe = atomicAdd(&cur[e], 1);
      csr[off[e] + pe] = n;
    }
    if (n >= n_lo && n < n_hi) {
      int pn = atomicAdd(&cur[N_EDGES + n], 1);
      csr[off[N_EDGES + n] + pn] = e;
    }
  }
}

// ---------------- x -> blocked-8 transpose ----------------

__global__ void k_xpose(const float* __restrict__ x, float* __restrict__ xb) {
  int t = blockIdx.x * 256 + threadIdx.x;
  if (t >= 16 * N_NODES) return;
  int g = t / N_NODES;
  int n = t - g * N_NODES;
  const float4* srcp = reinterpret_cast<const float4*>(x + (size_t)n * FIN + g * 8);
  float4 v0 = srcp[0], v1 = srcp[1];
  float4* dst = reinterpret_cast<float4*>(xb + (size_t)g * (N_NODES * 8) + (size_t)n * 8);
  dst[0] = v0; dst[1] = v1;
}

// ---------------- node -> edge gather (column-sharded, XCD-pinned) ----------------
// 16 groups x 625 blocks; block handles 32 edges (4 waves x 8 edges x 8 lanes).
// BUGFIX vs round 3: bi must strip the group bits (>>3).

__global__ __launch_bounds__(256) void k_passA(const float* __restrict__ xb,
                                               const int* __restrict__ csr,
                                               const int* __restrict__ off,
                                               const int* __restrict__ cnt,
                                               float* __restrict__ eb) {
  const int HALF = 5000;
  int b = blockIdx.x;
  int g = (b & 7) + ((b >= HALF) ? 8 : 0);
  int bi = ((b >= HALF) ? (b - HALF) : b) >> 3;     // block-within-group, [0,625)
  int lane = threadIdx.x & 63;
  int sub = lane >> 3, li = lane & 7;
  int e = bi * 32 + (threadIdx.x >> 6) * 8 + sub;   // < 20000 exactly
  int beg = off[e];
  int m = cnt[e];
  const float* src = xb + (size_t)g * (N_NODES * 8) + li;
  float acc = 0.f;
  int idxv = 0;
  for (int j = 0; j < m; ++j) {
    int jm = j & 7;
    if (jm == 0) {
      int p = j + li;
      idxv = (p < m) ? __builtin_nontemporal_load(csr + beg + p) : 0;
    }
    int node = __shfl(idxv, (lane & ~7) + jm);
    acc += src[(size_t)node * 8];
  }
  float binv = (m > 0) ? (1.f / (float)m) : 0.f;
  eb[(size_t)g * (N_EDGES * 8) + (size_t)e * 8 + li] = acc * binv;
}

// ---------------- edge-level GEMM: blocked-8 A @ W -> blocked-16 Out ----------------

template <int FOUT>
__global__ void k_gemm(const float* __restrict__ A, const float* __restrict__ W,
                       float* __restrict__ Out) {
  constexpr int CT = FOUT / 8;
  constexpr int NT = CT * 16;
  __shared__ float As[64][33];
  __shared__ float Ws[32][FOUT];
  int tid = threadIdx.x;
  int tx = tid % CT, ty = tid / CT;
  int row0 = blockIdx.x * 64;
  float acc[4][8];
#pragma unroll
  for (int i = 0; i < 4; ++i)
#pragma unroll
    for (int j = 0; j < 8; ++j) acc[i][j] = 0.f;

  for (int kc = 0; kc < FIN; kc += 32) {
    for (int i = tid; i < 64 * 32; i += NT) {
      int r = i >> 5, k = i & 31;
      int gr = row0 + r, kk = kc + k;
      As[r][k] = (gr < N_EDGES)
          ? A[(size_t)(kk >> 3) * (N_EDGES * 8) + (size_t)gr * 8 + (kk & 7)] : 0.f;
    }
    for (int i = tid; i < 32 * FOUT; i += NT) {
      int k = i / FOUT, cc = i % FOUT;
      Ws[k][cc] = W[(size_t)(kc + k) * FOUT + cc];
    }
    __syncthreads();
#pragma unroll
    for (int k = 0; k < 32; ++k) {
      float a[4];
#pragma unroll
      for (int i = 0; i < 4; ++i) a[i] = As[ty * 4 + i][k];
      float w[8];
#pragma unroll
      for (int j = 0; j < 8; ++j) w[j] = Ws[k][tx * 8 + j];
#pragma unroll
      for (int i = 0; i < 4; ++i)
#pragma unroll
        for (int j = 0; j < 8; ++j) acc[i][j] += a[i] * w[j];
    }
    __syncthreads();
  }
#pragma unroll
  for (int i = 0; i < 4; ++i) {
    int gr = row0 + ty * 4 + i;
    if (gr < N_EDGES) {
#pragma unroll
      for (int j = 0; j < 8; ++j) {
        int c = tx * 8 + j;
        Out[(size_t)(c >> 4) * (N_EDGES * 16) + (size_t)gr * 16 + (c & 15)] = acc[i][j];
      }
    }
  }
}

// ---------------- edge -> node gather, FOUT=128 (column-sharded) ----------------

template <bool RELU>
__global__ __launch_bounds__(256) void k_passB128(const float* __restrict__ eb2,
                                                  const int* __restrict__ csr,
                                                  const int* __restrict__ off,
                                                  const int* __restrict__ cnt,
                                                  const float* __restrict__ bias,
                                                  float* __restrict__ hb) {
  int b = blockIdx.x;
  int g = b & 7;
  int lane = threadIdx.x & 63;
  int sub = lane >> 4, li = lane & 15;
  int n = (b >> 3) * 16 + (threadIdx.x >> 6) * 4 + sub;   // < 100000 exactly
  int beg = off[N_EDGES + n];
  int m = cnt[N_EDGES + n];
  const float* src = eb2 + (size_t)g * (N_EDGES * 16) + li;
  float acc = 0.f;
  int idxv = 0;
  for (int j = 0; j < m; ++j) {
    int jm = j & 15;
    if (jm == 0) {
      int p = j + li;
      idxv = (p < m) ? __builtin_nontemporal_load(csr + beg + p) : 0;
    }
    int e = __shfl(idxv, (lane & ~15) + jm);
    acc += src[(size_t)e * 16];
  }
  float dinv = (m > 0) ? (1.f / (float)m) : 0.f;
  float o = acc * dinv + bias[g * 16 + li];
  if (RELU) o = fmaxf(o, 0.f);
  hb[(size_t)(2 * g + (li >> 3)) * (N_NODES * 8) + (size_t)n * 8 + (li & 7)] = o;
}

// ---------------- edge -> node gather, FOUT=64, row-major output ----------------

__global__ __launch_bounds__(256) void k_passB64(const float* __restrict__ eb2,
                                                 const int* __restrict__ csr,
                                                 const int* __restrict__ off,
                                                 const int* __restrict__ cnt,
                                                 const float* __restrict__ bias,
                                                 float* __restrict__ out) {
  int b = blockIdx.x;
  int gg = b & 7;
  int s = gg & 3, hh = gg >> 2;
  int lane = threadIdx.x & 63;
  int sub = lane >> 4, li = lane & 15;
  int n = hh * (N_NODES / 2) + (b >> 3) * 16 + (threadIdx.x >> 6) * 4 + sub;
  int beg = off[N_EDGES + n];
  int m = cnt[N_EDGES + n];
  const float* src = eb2 + (size_t)s * (N_EDGES * 16) + li;
  float acc = 0.f;
  int idxv = 0;
  for (int j = 0; j < m; ++j) {
    int jm = j & 15;
    if (jm == 0) {
      int p = j + li;
      idxv = (p < m) ? __builtin_nontemporal_load(csr + beg + p) : 0;
    }
    int e = __shfl(idxv, (lane & ~15) + jm);
    acc += src[(size_t)e * 16];
  }
  float dinv = (m > 0) ? (1.f / (float)m) : 0.f;
  float o = acc * dinv + bias[s * 16 + li];
  out[(size_t)n * 64 + s * 16 + li] = o;
}

// ---------------- launch ----------------

extern "C" void kernel_launch(void* const* d_in, const int* in_sizes, int n_in,
                              void* d_out, int out_size, void* d_ws, size_t ws_size,
                              hipStream_t stream) {
  const float* x  = (const float*)d_in[0];
  const float* W1 = (const float*)d_in[1];
  const float* b1 = (const float*)d_in[2];
  const float* W2 = (const float*)d_in[3];
  const float* b2 = (const float*)d_in[4];
  const float* W3 = (const float*)d_in[5];
  const float* b3 = (const float*)d_in[6];
  const int* nidx = (const int*)d_in[7];
  const int* eidx = (const int*)d_in[8];

  // workspace layout (bytes)
  const size_t OFF_CNT  = 0;          // int[120000]
  const size_t OFF_OFF  = 480000;     // int[120000]
  const size_t OFF_CUR  = 960000;     // int[120000]
  const size_t OFF_BSUM = 1440000;    // int[128]
  const size_t OFF_CSR  = 1441792;    // int[3200000]
  const size_t OFF_EB   = 14241792;   // float[16*20000*8]  ; hist partials alias (spill into EB2, dead before use)
  const size_t OFF_EB2  = 24481792;   // float[8*20000*16]
  const size_t OFF_H    = 34721792;   // float[16*100000*8] ; x_blk aliases h
  const size_t NEEDED   = 85921792;
  if (ws_size < NEEDED) return;

  char* ws = (char*)d_ws;
  int*   cnt   = (int*)(ws + OFF_CNT);
  int*   off   = (int*)(ws + OFF_OFF);
  int*   cur   = (int*)(ws + OFF_CUR);
  int*   bsum  = (int*)(ws + OFF_BSUM);
  int*   csr   = (int*)(ws + OFF_CSR);
  int*   part  = (int*)(ws + OFF_EB);    // dead after k_hreduce
  float* ebuf  = (float*)(ws + OFF_EB);
  float* ebuf2 = (float*)(ws + OFF_EB2);
  float* hbuf  = (float*)(ws + OFF_H);   // x_blk for layer 1, h_blk after
  float* out   = (float*)d_out;

  hipMemsetAsync(ws + OFF_CUR, 0, 480512, stream);  // cur + bsum

  // CSR build
  k_hist<<<10 * HSLICES, 256, 0, stream>>>(nidx, eidx, part);
  k_hreduce<<<(NSEG + 255) / 256, 256, 0, stream>>>(part, cnt);
  const int nb = (NSEG + 1023) / 1024;  // 118
  k_scan1<<<nb, 1024, 0, stream>>>(cnt, off, bsum);
  k_scan2<<<1, 128, 0, stream>>>(bsum, nb);
  k_scan3<<<nb, 1024, 0, stream>>>(off, cnt, bsum);
  k_fill<<<1024, 256, 0, stream>>>(nidx, eidx, off, cur, csr);

  // x -> blocked-8
  k_xpose<<<(16 * N_NODES + 255) / 256, 256, 0, stream>>>(x, hbuf);

  const int BLK_A  = 10000;   // 16 groups * 625 blocks (32 edges each)
  const int BLK_B  = 50000;   // 8 groups * 6250 blocks (16 nodes each)
  const int BLK_B3 = 25000;   // 8 lane-groups * 3125 blocks (16 nodes each)
  const int BLK_G  = (N_EDGES + 63) / 64;  // 313

  // layer 1
  k_passA<<<BLK_A, 256, 0, stream>>>(hbuf, csr, off, cnt, ebuf);
  k_gemm<128><<<BLK_G, 256, 0, stream>>>(ebuf, W1, ebuf2);
  k_passB128<true><<<BLK_B, 256, 0, stream>>>(ebuf2, csr, off, cnt, b1, hbuf);

  // layer 2
  k_passA<<<BLK_A, 256, 0, stream>>>(hbuf, csr, off, cnt, ebuf);
  k_gemm<128><<<BLK_G, 256, 0, stream>>>(ebuf, W2, ebuf2);
  k_passB128<true><<<BLK_B, 256, 0, stream>>>(ebuf2, csr, off, cnt, b2, hbuf);

  // layer 3
  k_passA<<<BLK_A, 256, 0, stream>>>(hbuf, csr, off, cnt, ebuf);
  k_gemm<64><<<BLK_G, 128, 0, stream>>>(ebuf, W3, ebuf2);
  k_passB64<<<BLK_B3, 256, 0, stream>>>(ebuf2, csr, off, cnt, b3, out);
}

// Round 5
// 920.018 us; speedup vs baseline: 2.0524x; 2.0524x over previous
//
#include <hip/hip_runtime.h>

#define N_NODES 100000
#define N_EDGES 20000
#define NNZV    1600000
#define NSEG    (N_EDGES + N_NODES)
#define FIN     128
#define NPART   8
#define E_PER_P (N_EDGES / NPART)   // 2500
#define N_PER_P (N_NODES / NPART)   // 12500
#define HSLICES 32

// ---------------- histogram count (LDS, atomic-free at device scope) ----------------

__global__ __launch_bounds__(256) void k_hist(const int* __restrict__ nidx,
                                              const int* __restrict__ eidx,
                                              int* __restrict__ part) {
  __shared__ int hist[12544];
  int r = blockIdx.x % 10, s = blockIdx.x / 10;
  const int* arr; int base, size, bin_off;
  if (r < 2) { arr = eidx; base = r * 10000; size = 10000; bin_off = r * 10000; }
  else { int ri = r - 2; arr = nidx; base = ri * N_PER_P; size = N_PER_P; bin_off = N_EDGES + ri * N_PER_P; }
  for (int i = threadIdx.x; i < size; i += 256) hist[i] = 0;
  __syncthreads();
  int lo = s * (NNZV / HSLICES), hi = lo + (NNZV / HSLICES);  // 50000 per slice
  for (int i = lo + threadIdx.x; i < hi; i += 256) {
    int v = __builtin_nontemporal_load(arr + i);
    unsigned d = (unsigned)(v - base);
    if (d < (unsigned)size) atomicAdd(&hist[d], 1);
  }
  __syncthreads();
  int* dst = part + (size_t)s * NSEG + bin_off;
  for (int i = threadIdx.x; i < size; i += 256) dst[i] = hist[i];
}

__global__ void k_hreduce(const int* __restrict__ part, int* __restrict__ cnt) {
  int b = blockIdx.x * 256 + threadIdx.x;
  if (b >= NSEG) return;
  int sum = 0;
#pragma unroll
  for (int s = 0; s < HSLICES; ++s) sum += part[(size_t)s * NSEG + b];
  cnt[b] = sum;
}

// ---------------- scans ----------------

__global__ void k_scan1(const int* __restrict__ cnt, int* __restrict__ incl,
                        int* __restrict__ bsum) {
  __shared__ int s[1024];
  int gid = blockIdx.x * 1024 + threadIdx.x;
  int v = (gid < NSEG) ? cnt[gid] : 0;
  s[threadIdx.x] = v;
  __syncthreads();
  for (int d = 1; d < 1024; d <<= 1) {
    int t = (threadIdx.x >= d) ? s[threadIdx.x - d] : 0;
    __syncthreads();
    s[threadIdx.x] += t;
    __syncthreads();
  }
  if (gid < NSEG) incl[gid] = s[threadIdx.x];
  if (threadIdx.x == 1023) bsum[blockIdx.x] = s[1023];
}

__global__ void k_scan2(int* __restrict__ bsum, int nb) {
  __shared__ int s[128];
  int v = (threadIdx.x < nb) ? bsum[threadIdx.x] : 0;
  s[threadIdx.x] = v;
  __syncthreads();
  for (int d = 1; d < 128; d <<= 1) {
    int t = (threadIdx.x >= (unsigned)d) ? s[threadIdx.x - d] : 0;
    __syncthreads();
    s[threadIdx.x] += t;
    __syncthreads();
  }
  if (threadIdx.x < nb) bsum[threadIdx.x] = s[threadIdx.x] - v;  // exclusive
}

__global__ void k_scan3(int* __restrict__ off, const int* __restrict__ cnt,
                        const int* __restrict__ bsum) {
  int gid = blockIdx.x * 1024 + threadIdx.x;
  if (gid < NSEG) off[gid] = off[gid] - cnt[gid] + bsum[blockIdx.x];
}

// ---------------- fill (destination-partitioned) ----------------

__global__ void k_fill(const int* __restrict__ nidx, const int* __restrict__ eidx,
                       const int* __restrict__ off, int* __restrict__ cur,
                       int* __restrict__ csr) {
  int p = blockIdx.x & (NPART - 1);
  int e_lo = p * E_PER_P, e_hi = e_lo + E_PER_P;
  int n_lo = p * N_PER_P, n_hi = n_lo + N_PER_P;
  int i = (blockIdx.x >> 3) * blockDim.x + threadIdx.x;
  int st = (gridDim.x >> 3) * blockDim.x;
  for (; i < NNZV; i += st) {
    int e = eidx[i], n = nidx[i];
    if (e >= e_lo && e < e_hi) {
      int pe = atomicAdd(&cur[e], 1);
      csr[off[e] + pe] = n;
    }
    if (n >= n_lo && n < n_hi) {
      int pn = atomicAdd(&cur[N_EDGES + n], 1);
      csr[off[N_EDGES + n] + pn] = e;
    }
  }
}

// ---------------- node -> edge gather: one wave per edge, 8-deep pipelined ----------------

__global__ __launch_bounds__(256) void k_passA(const float* __restrict__ xin,
                                               const int* __restrict__ csr,
                                               const int* __restrict__ off,
                                               const int* __restrict__ cnt,
                                               float* __restrict__ ebuf) {
  int wave = (blockIdx.x * blockDim.x + threadIdx.x) >> 6;
  int lane = threadIdx.x & 63;
  if (wave >= N_EDGES) return;
  int beg = off[wave];
  int m   = cnt[wave];
  const float* src = xin + lane * 2;
  float accx = 0.f, accy = 0.f;
  int idxv = 0;
  int j = 0;
  for (; j + 8 <= m; j += 8) {
    int jm = j & 63;
    if (jm == 0) {
      int p = j + lane;
      idxv = (p < m) ? __builtin_nontemporal_load(csr + beg + p) : 0;
    }
    int n0 = __shfl(idxv, jm);
    int n1 = __shfl(idxv, jm + 1);
    int n2 = __shfl(idxv, jm + 2);
    int n3 = __shfl(idxv, jm + 3);
    int n4 = __shfl(idxv, jm + 4);
    int n5 = __shfl(idxv, jm + 5);
    int n6 = __shfl(idxv, jm + 6);
    int n7 = __shfl(idxv, jm + 7);
    float2 v0 = *reinterpret_cast<const float2*>(src + (size_t)n0 * FIN);
    float2 v1 = *reinterpret_cast<const float2*>(src + (size_t)n1 * FIN);
    float2 v2 = *reinterpret_cast<const float2*>(src + (size_t)n2 * FIN);
    float2 v3 = *reinterpret_cast<const float2*>(src + (size_t)n3 * FIN);
    float2 v4 = *reinterpret_cast<const float2*>(src + (size_t)n4 * FIN);
    float2 v5 = *reinterpret_cast<const float2*>(src + (size_t)n5 * FIN);
    float2 v6 = *reinterpret_cast<const float2*>(src + (size_t)n6 * FIN);
    float2 v7 = *reinterpret_cast<const float2*>(src + (size_t)n7 * FIN);
    accx += ((v0.x + v1.x) + (v2.x + v3.x)) + ((v4.x + v5.x) + (v6.x + v7.x));
    accy += ((v0.y + v1.y) + (v2.y + v3.y)) + ((v4.y + v5.y) + (v6.y + v7.y));
  }
  for (; j < m; ++j) {
    int jm = j & 63;
    if (jm == 0) {
      int p = j + lane;
      idxv = (p < m) ? __builtin_nontemporal_load(csr + beg + p) : 0;
    }
    int n0 = __shfl(idxv, jm);
    float2 v = *reinterpret_cast<const float2*>(src + (size_t)n0 * FIN);
    accx += v.x; accy += v.y;
  }
  float binv = (m > 0) ? (1.f / (float)m) : 0.f;
  *reinterpret_cast<float2*>(ebuf + (size_t)wave * FIN + lane * 2) =
      make_float2(accx * binv, accy * binv);
}

// ---------------- edge-level GEMM: Out[20000][FOUT] = A[20000][128] @ W[128][FOUT] ----------------

template <int FOUT>
__global__ void k_gemm(const float* __restrict__ A, const float* __restrict__ W,
                       float* __restrict__ Out) {
  constexpr int CT = FOUT / 8;
  constexpr int NT = CT * 16;
  __shared__ float As[64][33];
  __shared__ float Ws[32][FOUT];
  int tid = threadIdx.x;
  int tx = tid % CT, ty = tid / CT;
  int row0 = blockIdx.x * 64;
  float acc[4][8];
#pragma unroll
  for (int i = 0; i < 4; ++i)
#pragma unroll
    for (int j = 0; j < 8; ++j) acc[i][j] = 0.f;

  for (int kc = 0; kc < FIN; kc += 32) {
    for (int i = tid; i < 64 * 32; i += NT) {
      int r = i >> 5, k = i & 31;
      int gr = row0 + r;
      As[r][k] = (gr < N_EDGES) ? A[(size_t)gr * FIN + kc + k] : 0.f;
    }
    for (int i = tid; i < 32 * FOUT; i += NT) {
      int k = i / FOUT, cc = i % FOUT;
      Ws[k][cc] = W[(size_t)(kc + k) * FOUT + cc];
    }
    __syncthreads();
#pragma unroll
    for (int k = 0; k < 32; ++k) {
      float a[4];
#pragma unroll
      for (int i = 0; i < 4; ++i) a[i] = As[ty * 4 + i][k];
      float w[8];
#pragma unroll
      for (int j = 0; j < 8; ++j) w[j] = Ws[k][tx * 8 + j];
#pragma unroll
      for (int i = 0; i < 4; ++i)
#pragma unroll
        for (int j = 0; j < 8; ++j) acc[i][j] += a[i] * w[j];
    }
    __syncthreads();
  }
#pragma unroll
  for (int i = 0; i < 4; ++i) {
    int gr = row0 + ty * 4 + i;
    if (gr < N_EDGES) {
#pragma unroll
      for (int j = 0; j < 8; ++j)
        Out[(size_t)gr * FOUT + tx * 8 + j] = acc[i][j];
    }
  }
}

// ---------------- edge -> node gather, FOUT=128, 8-deep pipelined ----------------

template <bool RELU>
__global__ __launch_bounds__(256) void k_passB128(const float* __restrict__ efeat,
                                                  const int* __restrict__ csr,
                                                  const int* __restrict__ off,
                                                  const int* __restrict__ cnt,
                                                  const float* __restrict__ bias,
                                                  float* __restrict__ out) {
  int wave = (blockIdx.x * blockDim.x + threadIdx.x) >> 6;
  int lane = threadIdx.x & 63;
  if (wave >= N_NODES) return;
  int beg = off[N_EDGES + wave];
  int m   = cnt[N_EDGES + wave];
  const float* src = efeat + lane * 2;
  float accx = 0.f, accy = 0.f;
  int idxv = 0;
  int j = 0;
  for (; j + 8 <= m; j += 8) {
    int jm = j & 63;
    if (jm == 0) {
      int p = j + lane;
      idxv = (p < m) ? __builtin_nontemporal_load(csr + beg + p) : 0;
    }
    int n0 = __shfl(idxv, jm);
    int n1 = __shfl(idxv, jm + 1);
    int n2 = __shfl(idxv, jm + 2);
    int n3 = __shfl(idxv, jm + 3);
    int n4 = __shfl(idxv, jm + 4);
    int n5 = __shfl(idxv, jm + 5);
    int n6 = __shfl(idxv, jm + 6);
    int n7 = __shfl(idxv, jm + 7);
    float2 v0 = *reinterpret_cast<const float2*>(src + (size_t)n0 * 128);
    float2 v1 = *reinterpret_cast<const float2*>(src + (size_t)n1 * 128);
    float2 v2 = *reinterpret_cast<const float2*>(src + (size_t)n2 * 128);
    float2 v3 = *reinterpret_cast<const float2*>(src + (size_t)n3 * 128);
    float2 v4 = *reinterpret_cast<const float2*>(src + (size_t)n4 * 128);
    float2 v5 = *reinterpret_cast<const float2*>(src + (size_t)n5 * 128);
    float2 v6 = *reinterpret_cast<const float2*>(src + (size_t)n6 * 128);
    float2 v7 = *reinterpret_cast<const float2*>(src + (size_t)n7 * 128);
    accx += ((v0.x + v1.x) + (v2.x + v3.x)) + ((v4.x + v5.x) + (v6.x + v7.x));
    accy += ((v0.y + v1.y) + (v2.y + v3.y)) + ((v4.y + v5.y) + (v6.y + v7.y));
  }
  for (; j < m; ++j) {
    int jm = j & 63;
    if (jm == 0) {
      int p = j + lane;
      idxv = (p < m) ? __builtin_nontemporal_load(csr + beg + p) : 0;
    }
    int n0 = __shfl(idxv, jm);
    float2 v = *reinterpret_cast<const float2*>(src + (size_t)n0 * 128);
    accx += v.x; accy += v.y;
  }
  float dinv = (m > 0) ? (1.f / (float)m) : 0.f;
  float ox = accx * dinv + bias[lane * 2];
  float oy = accy * dinv + bias[lane * 2 + 1];
  if (RELU) { ox = fmaxf(ox, 0.f); oy = fmaxf(oy, 0.f); }
  *reinterpret_cast<float2*>(out + (size_t)wave * 128 + lane * 2) = make_float2(ox, oy);
}

// ---------------- edge -> node gather, FOUT=64, 8-deep pipelined ----------------

__global__ __launch_bounds__(256) void k_passB64(const float* __restrict__ efeat,
                                                 const int* __restrict__ csr,
                                                 const int* __restrict__ off,
                                                 const int* __restrict__ cnt,
                                                 const float* __restrict__ bias,
                                                 float* __restrict__ out) {
  int wave = (blockIdx.x * blockDim.x + threadIdx.x) >> 6;
  int lane = threadIdx.x & 63;
  if (wave >= N_NODES) return;
  int beg = off[N_EDGES + wave];
  int m   = cnt[N_EDGES + wave];
  const float* src = efeat + lane;
  float acc = 0.f;
  int idxv = 0;
  int j = 0;
  for (; j + 8 <= m; j += 8) {
    int jm = j & 63;
    if (jm == 0) {
      int p = j + lane;
      idxv = (p < m) ? __builtin_nontemporal_load(csr + beg + p) : 0;
    }
    int n0 = __shfl(idxv, jm);
    int n1 = __shfl(idxv, jm + 1);
    int n2 = __shfl(idxv, jm + 2);
    int n3 = __shfl(idxv, jm + 3);
    int n4 = __shfl(idxv, jm + 4);
    int n5 = __shfl(idxv, jm + 5);
    int n6 = __shfl(idxv, jm + 6);
    int n7 = __shfl(idxv, jm + 7);
    float v0 = src[(size_t)n0 * 64];
    float v1 = src[(size_t)n1 * 64];
    float v2 = src[(size_t)n2 * 64];
    float v3 = src[(size_t)n3 * 64];
    float v4 = src[(size_t)n4 * 64];
    float v5 = src[(size_t)n5 * 64];
    float v6 = src[(size_t)n6 * 64];
    float v7 = src[(size_t)n7 * 64];
    acc += ((v0 + v1) + (v2 + v3)) + ((v4 + v5) + (v6 + v7));
  }
  for (; j < m; ++j) {
    int jm = j & 63;
    if (jm == 0) {
      int p = j + lane;
      idxv = (p < m) ? __builtin_nontemporal_load(csr + beg + p) : 0;
    }
    int n0 = __shfl(idxv, jm);
    acc += src[(size_t)n0 * 64];
  }
  float dinv = (m > 0) ? (1.f / (float)m) : 0.f;
  out[(size_t)wave * 64 + lane] = acc * dinv + bias[lane];
}

// ---------------- launch ----------------

extern "C" void kernel_launch(void* const* d_in, const int* in_sizes, int n_in,
                              void* d_out, int out_size, void* d_ws, size_t ws_size,
                              hipStream_t stream) {
  const float* x  = (const float*)d_in[0];
  const float* W1 = (const float*)d_in[1];
  const float* b1 = (const float*)d_in[2];
  const float* W2 = (const float*)d_in[3];
  const float* b2 = (const float*)d_in[4];
  const float* W3 = (const float*)d_in[5];
  const float* b3 = (const float*)d_in[6];
  const int* nidx = (const int*)d_in[7];
  const int* eidx = (const int*)d_in[8];

  // workspace layout (bytes)
  const size_t OFF_CNT  = 0;          // int[120000]
  const size_t OFF_OFF  = 480000;     // int[120000]
  const size_t OFF_CUR  = 960000;     // int[120000]
  const size_t OFF_BSUM = 1440000;    // int[128]
  const size_t OFF_CSR  = 1441792;    // int[3200000]
  const size_t OFF_EB   = 14241792;   // float[20000*128] ; hist partials alias (spill into EB2, dead before use)
  const size_t OFF_EB2  = 24481792;   // float[20000*128]
  const size_t OFF_H    = 34721792;   // float[100000*128]
  const size_t NEEDED   = 85921792;
  if (ws_size < NEEDED) return;

  char* ws = (char*)d_ws;
  int*   cnt   = (int*)(ws + OFF_CNT);
  int*   off   = (int*)(ws + OFF_OFF);
  int*   cur   = (int*)(ws + OFF_CUR);
  int*   bsum  = (int*)(ws + OFF_BSUM);
  int*   csr   = (int*)(ws + OFF_CSR);
  int*   part  = (int*)(ws + OFF_EB);    // dead after k_hreduce
  float* ebuf  = (float*)(ws + OFF_EB);
  float* ebuf2 = (float*)(ws + OFF_EB2);
  float* h     = (float*)(ws + OFF_H);
  float* out   = (float*)d_out;

  hipMemsetAsync(ws + OFF_CUR, 0, 480512, stream);  // cur + bsum

  // CSR build
  k_hist<<<10 * HSLICES, 256, 0, stream>>>(nidx, eidx, part);
  k_hreduce<<<(NSEG + 255) / 256, 256, 0, stream>>>(part, cnt);
  const int nb = (NSEG + 1023) / 1024;  // 118
  k_scan1<<<nb, 1024, 0, stream>>>(cnt, off, bsum);
  k_scan2<<<1, 128, 0, stream>>>(bsum, nb);
  k_scan3<<<nb, 1024, 0, stream>>>(off, cnt, bsum);
  k_fill<<<1024, 256, 0, stream>>>(nidx, eidx, off, cur, csr);

  const int BLK_A = (N_EDGES * 64 + 255) / 256;   // 5000
  const int BLK_B = (N_NODES * 64 + 255) / 256;   // 25000
  const int BLK_G = (N_EDGES + 63) / 64;          // 313

  // layer 1: x -> h (relu)
  k_passA<<<BLK_A, 256, 0, stream>>>(x, csr, off, cnt, ebuf);
  k_gemm<128><<<BLK_G, 256, 0, stream>>>(ebuf, W1, ebuf2);
  k_passB128<true><<<BLK_B, 256, 0, stream>>>(ebuf2, csr, off, cnt, b1, h);

  // layer 2: h -> h (relu)
  k_passA<<<BLK_A, 256, 0, stream>>>(h, csr, off, cnt, ebuf);
  k_gemm<128><<<BLK_G, 256, 0, stream>>>(ebuf, W2, ebuf2);
  k_passB128<true><<<BLK_B, 256, 0, stream>>>(ebuf2, csr, off, cnt, b2, h);

  // layer 3: h -> out (no relu)
  k_passA<<<BLK_A, 256, 0, stream>>>(h, csr, off, cnt, ebuf);
  k_gemm<64><<<BLK_G, 128, 0, stream>>>(ebuf, W3, ebuf2);
  k_passB64<<<BLK_B, 256, 0, stream>>>(ebuf2, csr, off, cnt, b3, out);
}